// Round 3
// baseline (2007.278 us; speedup 1.0000x reference)
//
#include <hip/hip_runtime.h>
#include <stdint.h>

#define ROWS 4096
#define DIM 1024
#define VOCAB 32000
#define BM 128
#define BN 128
#define BK 64
#define LDK 72              // padded LDS row stride (f16 elems): 144 B
#define NTILES (VOCAB / BN) // 250
#define TILES_PER_WG 10
#define NCHUNKS (NTILES / TILES_PER_WG) // 25
#define SCALE 2048.0f       // keeps f16 lo-plane normal; argmax is scale-invariant

typedef float floatx4 __attribute__((ext_vector_type(4)));
typedef _Float16 f16x8 __attribute__((ext_vector_type(8)));
typedef _Float16 f16x4 __attribute__((ext_vector_type(4)));

// ---- kernel 0: zero the per-row argmax keys (ws is poisoned 0xAA each call) ----
__global__ void init_keys(unsigned long long* __restrict__ keys) {
    int i = blockIdx.x * 256 + threadIdx.x;
    if (i < ROWS) keys[i] = 0ull;
}

// ---- kernel 1: f32 inputs -> scaled f16 hi/lo split -> 3-product MFMA GEMM + argmax ----
// grid = (ROWS/BM) * NCHUNKS blocks; block = 256 (4 waves, 2x2 wave grid)
__global__ __launch_bounds__(256, 2) void gemm_argmax(
    const float* __restrict__ emb, const float* __restrict__ noi,
    const float* __restrict__ table, unsigned long long* __restrict__ keys) {
    __shared__ __align__(16) _Float16 Ah[BM * LDK];
    __shared__ __align__(16) _Float16 Al[BM * LDK];
    __shared__ __align__(16) _Float16 Bh[BN * LDK];
    __shared__ __align__(16) _Float16 Bl[BN * LDK];
    __shared__ unsigned long long redk[BM];

    const int tid = threadIdx.x;
    const int wave = tid >> 6, lane = tid & 63;
    const int quad = lane >> 4, lq = lane & 15;
    const int rb = blockIdx.x / NCHUNKS, chunk = blockIdx.x % NCHUNKS;
    const int row0 = rb * BM;
    const int wm = (wave & 1) * 64, wn = (wave >> 1) * 64;

    if (tid < BM) redk[tid] = 0ull; // many __syncthreads before first use

    // ---- runtime layout probes: learn each accumulator slot's logical (m,n) ----
    // Under MY load convention (lane holds X[lq][k=quad*8+j]):
    //   c1 = mfma(idx,one) -> slot value = logical m;  c2 = mfma(one,idx) -> logical n.
    union PF { f16x8 v; _Float16 s[8]; } fidx, fone;
#pragma unroll
    for (int j = 0; j < 8; j++) { fidx.s[j] = (_Float16)0.0f; fone.s[j] = (_Float16)0.0f; }
    if (quad == 0) {
        fidx.s[0] = (_Float16)(float)lq; // exact for 0..15
        fone.s[0] = (_Float16)1.0f;
    }
    floatx4 c1 = {0.f, 0.f, 0.f, 0.f}, c2 = {0.f, 0.f, 0.f, 0.f};
    c1 = __builtin_amdgcn_mfma_f32_16x16x32_f16(fidx.v, fone.v, c1, 0, 0, 0);
    c2 = __builtin_amdgcn_mfma_f32_16x16x32_f16(fone.v, fidx.v, c2, 0, 0, 0);
    int m_of[4], n_of[4];
#pragma unroll
    for (int r = 0; r < 4; r++) {
        m_of[r] = (int)(c1[r] + 0.5f);
        n_of[r] = (int)(c2[r] + 0.5f);
    }

    float rmax[16];
    int ridx[16];
#pragma unroll
    for (int i = 0; i < 16; i++) { rmax[i] = -3.4e38f; ridx[i] = 0; }

    for (int t = 0; t < TILES_PER_WG; ++t) {
        const int n0 = (chunk * TILES_PER_WG + t) * BN;
        floatx4 acc[4][4];
#pragma unroll
        for (int mi = 0; mi < 4; mi++)
#pragma unroll
            for (int ni = 0; ni < 4; ni++)
#pragma unroll
                for (int r = 0; r < 4; r++) acc[mi][ni][r] = 0.0f;

        for (int kt = 0; kt < DIM / BK; ++kt) {
            const int k0 = kt * BK;
            __syncthreads(); // protect LDS reads of previous iteration
            // A: 128 rows x 64 cols f32 = 2048 float4 chunks; same for B
#pragma unroll
            for (int i = 0; i < 8; i++) {
                int c = i * 256 + tid;
                int r = c >> 4, q = c & 15; // 16 float4 per row of 64 cols
                floatx4 e = *(const floatx4*)(emb + (size_t)(row0 + r) * DIM + k0 + q * 4);
                floatx4 n = *(const floatx4*)(noi + (size_t)(row0 + r) * DIM + k0 + q * 4);
                floatx4 b = *(const floatx4*)(table + (size_t)(n0 + r) * DIM + k0 + q * 4);
                f16x4 ah, al, bh, bl;
#pragma unroll
                for (int j = 0; j < 4; j++) {
                    float pa = (e[j] + n[j]) * SCALE;
                    _Float16 h = (_Float16)pa;
                    ah[j] = h;
                    al[j] = (_Float16)(pa - (float)h);
                    float pb = b[j] * SCALE;
                    _Float16 hb = (_Float16)pb;
                    bh[j] = hb;
                    bl[j] = (_Float16)(pb - (float)hb);
                }
                *(f16x4*)(Ah + r * LDK + q * 4) = ah;
                *(f16x4*)(Al + r * LDK + q * 4) = al;
                *(f16x4*)(Bh + r * LDK + q * 4) = bh;
                *(f16x4*)(Bl + r * LDK + q * 4) = bl;
            }
            __syncthreads();
#pragma unroll
            for (int ks = 0; ks < BK; ks += 32) {
                f16x8 bhf[4], blf[4], ahf[4], alf[4];
#pragma unroll
                for (int i = 0; i < 4; i++) {
                    bhf[i] = *(const f16x8*)(Bh + (wn + i * 16 + lq) * LDK + ks + quad * 8);
                    blf[i] = *(const f16x8*)(Bl + (wn + i * 16 + lq) * LDK + ks + quad * 8);
                    ahf[i] = *(const f16x8*)(Ah + (wm + i * 16 + lq) * LDK + ks + quad * 8);
                    alf[i] = *(const f16x8*)(Al + (wm + i * 16 + lq) * LDK + ks + quad * 8);
                }
#pragma unroll
                for (int mi = 0; mi < 4; mi++)
#pragma unroll
                    for (int ni = 0; ni < 4; ni++) {
                        acc[mi][ni] = __builtin_amdgcn_mfma_f32_16x16x32_f16(
                            ahf[mi], bhf[ni], acc[mi][ni], 0, 0, 0);
                        acc[mi][ni] = __builtin_amdgcn_mfma_f32_16x16x32_f16(
                            ahf[mi], blf[ni], acc[mi][ni], 0, 0, 0);
                        acc[mi][ni] = __builtin_amdgcn_mfma_f32_16x16x32_f16(
                            alf[mi], bhf[ni], acc[mi][ni], 0, 0, 0);
                    }
            }
        }
        // fold this n-tile into per-row running argmax (probed layout)
#pragma unroll
        for (int mi = 0; mi < 4; mi++)
#pragma unroll
            for (int ni = 0; ni < 4; ni++)
#pragma unroll
                for (int r = 0; r < 4; r++) {
                    float v = acc[mi][ni][r];
                    int col = n0 + wn + ni * 16 + n_of[r];
                    int s = mi * 4 + r;
                    if (v > rmax[s] || (v == rmax[s] && col < ridx[s])) {
                        rmax[s] = v;
                        ridx[s] = col;
                    }
                }
    }

    // reduce: LDS atomicMax keyed by probed row, then one global atomic per row
#pragma unroll
    for (int s = 0; s < 16; ++s) {
        int mi = s >> 2, r = s & 3;
        int rowl = wm + mi * 16 + m_of[r];
        union { float f; uint32_t i; } u;
        u.f = rmax[s];
        uint32_t ord = (u.i & 0x80000000u) ? ~u.i : (u.i | 0x80000000u);
        // invert idx so equal values prefer the SMALLEST vocab index (np tie-break)
        unsigned long long key =
            ((unsigned long long)ord << 32) | (uint32_t)(~(uint32_t)ridx[s]);
        atomicMax(&redk[rowl], key);
    }
    __syncthreads();
    if (tid < BM) atomicMax(&keys[row0 + tid], redk[tid]);
}

// ---- kernel 2: gather winning table rows (f32) to output ----
__global__ void gather_kernel(const unsigned long long* __restrict__ keys,
                              const float* __restrict__ table,
                              float* __restrict__ out) {
    int row = blockIdx.x;
    unsigned long long key = keys[row];
    uint32_t ix = ~(uint32_t)(key & 0xFFFFFFFFull);
    const floatx4* src = (const floatx4*)(table + (size_t)ix * DIM);
    floatx4* dst = (floatx4*)(out + (size_t)row * DIM);
    dst[threadIdx.x] = src[threadIdx.x]; // block = 256: 256 * 16B = 4 KB row
}

extern "C" void kernel_launch(void* const* d_in, const int* in_sizes, int n_in,
                              void* d_out, int out_size, void* d_ws, size_t ws_size,
                              hipStream_t stream) {
    (void)in_sizes; (void)n_in; (void)out_size; (void)ws_size;
    const float* emb = (const float*)d_in[0];
    const float* table = (const float*)d_in[1];
    const float* noi = (const float*)d_in[2];
    float* out = (float*)d_out;

    unsigned long long* keys = (unsigned long long*)d_ws; // 32 KB only

    init_keys<<<ROWS / 256, 256, 0, stream>>>(keys);
    gemm_argmax<<<(ROWS / BM) * NCHUNKS, 256, 0, stream>>>(emb, noi, table, keys);
    gather_kernel<<<ROWS, 256, 0, stream>>>(keys, table, out);
}

// Round 4
// 1015.823 us; speedup vs baseline: 1.9760x; 1.9760x over previous
//
#include <hip/hip_runtime.h>
#include <stdint.h>

#define ROWS 4096
#define DIM 1024
#define VOCAB 32000
#define BM 128
#define BN 128
#define NTILES (VOCAB / BN)  // 250
#define NCHUNKS 24           // 32 row-blocks * 24 = 768 blocks = 3/CU, all co-resident
#define SCALE 2048.0f        // keeps f16 lo-plane normal; argmax is scale-invariant

typedef float floatx4 __attribute__((ext_vector_type(4)));
typedef _Float16 f16x8 __attribute__((ext_vector_type(8)));
typedef _Float16 f16x4 __attribute__((ext_vector_type(4)));

__device__ __forceinline__ void load_lds16(const _Float16* g, _Float16* l) {
    __builtin_amdgcn_global_load_lds(
        (const __attribute__((address_space(1))) uint32_t*)g,
        (__attribute__((address_space(3))) uint32_t*)l, 16, 0, 0);
}

// ---- kernel 0: zero the per-row argmax keys (ws is poisoned 0xAA each call) ----
__global__ void init_keys(unsigned long long* __restrict__ keys) {
    int i = blockIdx.x * 256 + threadIdx.x;
    if (i < ROWS) keys[i] = 0ull;
}

// ---- split kernels: f32 -> scaled f16 hi/lo planes (numerics identical to R3) ----
__global__ void split_sum(const float* __restrict__ x, const float* __restrict__ y,
                          _Float16* __restrict__ hi, _Float16* __restrict__ lo) {
    size_t i = ((size_t)blockIdx.x * 256 + threadIdx.x) * 8;
    floatx4 a = *(const floatx4*)(x + i);
    floatx4 b = *(const floatx4*)(x + i + 4);
    floatx4 c = *(const floatx4*)(y + i);
    floatx4 d = *(const floatx4*)(y + i + 4);
    f16x8 h, l;
#pragma unroll
    for (int j = 0; j < 4; j++) {
        float p = (a[j] + c[j]) * SCALE;
        _Float16 hh = (_Float16)p;
        h[j] = hh; l[j] = (_Float16)(p - (float)hh);
        float q = (b[j] + d[j]) * SCALE;
        _Float16 hq = (_Float16)q;
        h[4 + j] = hq; l[4 + j] = (_Float16)(q - (float)hq);
    }
    *(f16x8*)(hi + i) = h;
    *(f16x8*)(lo + i) = l;
}

__global__ void split_one(const float* __restrict__ x,
                          _Float16* __restrict__ hi, _Float16* __restrict__ lo) {
    size_t i = ((size_t)blockIdx.x * 256 + threadIdx.x) * 8;
    floatx4 a = *(const floatx4*)(x + i);
    floatx4 b = *(const floatx4*)(x + i + 4);
    f16x8 h, l;
#pragma unroll
    for (int j = 0; j < 4; j++) {
        float p = a[j] * SCALE;
        _Float16 hh = (_Float16)p;
        h[j] = hh; l[j] = (_Float16)(p - (float)hh);
        float q = b[j] * SCALE;
        _Float16 hq = (_Float16)q;
        h[4 + j] = hq; l[4 + j] = (_Float16)(q - (float)hq);
    }
    *(f16x8*)(hi + i) = h;
    *(f16x8*)(lo + i) = l;
}

// ---- main GEMM+argmax on precomputed planes, global_load_lds staging ----
// grid = 32 * NCHUNKS = 768; block = 256 (4 waves, 2x2 wave grid). BK=32.
__global__ __launch_bounds__(256, 3) void gemm_argmax_pre(
    const _Float16* __restrict__ Ah, const _Float16* __restrict__ Al,
    const _Float16* __restrict__ Bh, const _Float16* __restrict__ Bl,
    unsigned long long* __restrict__ keys) {
    __shared__ __align__(16) _Float16 sAh[BM * 32];
    __shared__ __align__(16) _Float16 sAl[BM * 32];
    __shared__ __align__(16) _Float16 sBh[BN * 32];
    __shared__ __align__(16) _Float16 sBl[BN * 32];
    __shared__ unsigned long long redk[BM];

    const int tid = threadIdx.x;
    const int w = tid >> 6, lane = tid & 63;
    const int quad = lane >> 4, lq = lane & 15;
    const int rb = blockIdx.x / NCHUNKS, chunk = blockIdx.x % NCHUNKS;
    const int row0 = rb * BM;
    const int wm = (w & 1) * 64, wn = (w >> 1) * 64;
    const int tstart = chunk * NTILES / NCHUNKS;
    const int tend = (chunk + 1) * NTILES / NCHUNKS;

    if (tid < BM) redk[tid] = 0ull; // barriers intervene before use

    // runtime layout probe (same as R3): c1 slot value = logical m, c2 = logical n
    union PF { f16x8 v; _Float16 s[8]; } fidx, fone;
#pragma unroll
    for (int j = 0; j < 8; j++) { fidx.s[j] = (_Float16)0.0f; fone.s[j] = (_Float16)0.0f; }
    if (quad == 0) { fidx.s[0] = (_Float16)(float)lq; fone.s[0] = (_Float16)1.0f; }
    floatx4 c1 = {0.f, 0.f, 0.f, 0.f}, c2 = {0.f, 0.f, 0.f, 0.f};
    c1 = __builtin_amdgcn_mfma_f32_16x16x32_f16(fidx.v, fone.v, c1, 0, 0, 0);
    c2 = __builtin_amdgcn_mfma_f32_16x16x32_f16(fone.v, fidx.v, c2, 0, 0, 0);
    int m_of[4], n_of[4];
#pragma unroll
    for (int r = 0; r < 4; r++) {
        m_of[r] = (int)(c1[r] + 0.5f);
        n_of[r] = (int)(c2[r] + 0.5f);
    }

    // wave -> plane assignment for staging (wave-uniform)
    const _Float16* gsrcA = (w == 0) ? (Ah + (size_t)row0 * DIM)
                        : (w == 1) ? (Al + (size_t)row0 * DIM)
                        : (w == 2) ? Bh : Bl; // B base gets +n0*DIM per tile
    _Float16* ldst = (w == 0) ? sAh : (w == 1) ? sAl : (w == 2) ? sBh : sBl;

    float rmax[16];
    int ridx[16];
#pragma unroll
    for (int i = 0; i < 16; i++) { rmax[i] = -3.4e38f; ridx[i] = 0; }

    for (int t = tstart; t < tend; ++t) {
        const int n0 = t * BN;
        const _Float16* gsrc = (w < 2) ? gsrcA : (gsrcA + (size_t)n0 * DIM);
        floatx4 acc[4][4];
#pragma unroll
        for (int mi = 0; mi < 4; mi++)
#pragma unroll
            for (int ni = 0; ni < 4; ni++)
#pragma unroll
                for (int r = 0; r < 4; r++) acc[mi][ni][r] = 0.0f;

        for (int kt = 0; kt < DIM / 32; ++kt) {
            const int k0 = kt * 32;
            __syncthreads(); // previous tile's LDS reads complete
            // each wave stages one full plane: 128 rows x 32 f16 = 8 KB = 8 chunks
            // lane l deposits 16 B at (chunk base + l*16): row=c*16+(l>>2), piece=l&3
#pragma unroll
            for (int c = 0; c < 8; c++) {
                const _Float16* g =
                    gsrc + (size_t)(c * 16 + (lane >> 2)) * DIM + k0 + (lane & 3) * 8;
                load_lds16(g, ldst + c * 512);
            }
            __syncthreads(); // staged data visible (compiler drains vmcnt)

            f16x8 ahf[4], alf[4];
#pragma unroll
            for (int i = 0; i < 4; i++) {
                int r = wm + i * 16 + lq;
                ahf[i] = *(const f16x8*)(sAh + r * 32 + quad * 8);
                alf[i] = *(const f16x8*)(sAl + r * 32 + quad * 8);
            }
#pragma unroll
            for (int ni = 0; ni < 4; ni++) {
                int r = wn + ni * 16 + lq;
                f16x8 bh = *(const f16x8*)(sBh + r * 32 + quad * 8);
                f16x8 bl = *(const f16x8*)(sBl + r * 32 + quad * 8);
#pragma unroll
                for (int mi = 0; mi < 4; mi++) {
                    acc[mi][ni] = __builtin_amdgcn_mfma_f32_16x16x32_f16(
                        ahf[mi], bh, acc[mi][ni], 0, 0, 0);
                    acc[mi][ni] = __builtin_amdgcn_mfma_f32_16x16x32_f16(
                        ahf[mi], bl, acc[mi][ni], 0, 0, 0);
                    acc[mi][ni] = __builtin_amdgcn_mfma_f32_16x16x32_f16(
                        alf[mi], bh, acc[mi][ni], 0, 0, 0);
                }
            }
        }
        // fold this n-tile into per-row running argmax (probed layout)
#pragma unroll
        for (int mi = 0; mi < 4; mi++)
#pragma unroll
            for (int ni = 0; ni < 4; ni++)
#pragma unroll
                for (int r = 0; r < 4; r++) {
                    float v = acc[mi][ni][r];
                    int col = n0 + wn + ni * 16 + n_of[r];
                    int s = mi * 4 + r;
                    if (v > rmax[s] || (v == rmax[s] && col < ridx[s])) {
                        rmax[s] = v;
                        ridx[s] = col;
                    }
                }
    }

    // reduce: LDS atomicMax keyed by probed row, then one global atomic per row
#pragma unroll
    for (int s = 0; s < 16; ++s) {
        int mi = s >> 2, r = s & 3;
        int rowl = wm + mi * 16 + m_of[r];
        union { float f; uint32_t i; } u;
        u.f = rmax[s];
        uint32_t ord = (u.i & 0x80000000u) ? ~u.i : (u.i | 0x80000000u);
        unsigned long long key =
            ((unsigned long long)ord << 32) | (uint32_t)(~(uint32_t)ridx[s]);
        atomicMax(&redk[rowl], key);
    }
    __syncthreads();
    if (tid < BM) atomicMax(&keys[row0 + tid], redk[tid]);
}

// ================== fallback path (R3, verified): in-kernel split ==================
#define BKF 64
#define LDKF 72
#define TILES_PER_WGF 10
#define NCHUNKSF 25

__global__ __launch_bounds__(256, 2) void gemm_argmax_fused(
    const float* __restrict__ emb, const float* __restrict__ noi,
    const float* __restrict__ table, unsigned long long* __restrict__ keys) {
    __shared__ __align__(16) _Float16 Ah[BM * LDKF];
    __shared__ __align__(16) _Float16 Al[BM * LDKF];
    __shared__ __align__(16) _Float16 Bh[BN * LDKF];
    __shared__ __align__(16) _Float16 Bl[BN * LDKF];
    __shared__ unsigned long long redk[BM];

    const int tid = threadIdx.x;
    const int wave = tid >> 6, lane = tid & 63;
    const int quad = lane >> 4, lq = lane & 15;
    const int rb = blockIdx.x / NCHUNKSF, chunk = blockIdx.x % NCHUNKSF;
    const int row0 = rb * BM;
    const int wm = (wave & 1) * 64, wn = (wave >> 1) * 64;

    if (tid < BM) redk[tid] = 0ull;

    union PF { f16x8 v; _Float16 s[8]; } fidx, fone;
#pragma unroll
    for (int j = 0; j < 8; j++) { fidx.s[j] = (_Float16)0.0f; fone.s[j] = (_Float16)0.0f; }
    if (quad == 0) { fidx.s[0] = (_Float16)(float)lq; fone.s[0] = (_Float16)1.0f; }
    floatx4 c1 = {0.f, 0.f, 0.f, 0.f}, c2 = {0.f, 0.f, 0.f, 0.f};
    c1 = __builtin_amdgcn_mfma_f32_16x16x32_f16(fidx.v, fone.v, c1, 0, 0, 0);
    c2 = __builtin_amdgcn_mfma_f32_16x16x32_f16(fone.v, fidx.v, c2, 0, 0, 0);
    int m_of[4], n_of[4];
#pragma unroll
    for (int r = 0; r < 4; r++) {
        m_of[r] = (int)(c1[r] + 0.5f);
        n_of[r] = (int)(c2[r] + 0.5f);
    }

    float rmax[16];
    int ridx[16];
#pragma unroll
    for (int i = 0; i < 16; i++) { rmax[i] = -3.4e38f; ridx[i] = 0; }

    for (int t = 0; t < TILES_PER_WGF; ++t) {
        const int n0 = (chunk * TILES_PER_WGF + t) * BN;
        floatx4 acc[4][4];
#pragma unroll
        for (int mi = 0; mi < 4; mi++)
#pragma unroll
            for (int ni = 0; ni < 4; ni++)
#pragma unroll
                for (int r = 0; r < 4; r++) acc[mi][ni][r] = 0.0f;

        for (int kt = 0; kt < DIM / BKF; ++kt) {
            const int k0 = kt * BKF;
            __syncthreads();
#pragma unroll
            for (int i = 0; i < 8; i++) {
                int c = i * 256 + tid;
                int r = c >> 4, q = c & 15;
                floatx4 e = *(const floatx4*)(emb + (size_t)(row0 + r) * DIM + k0 + q * 4);
                floatx4 n = *(const floatx4*)(noi + (size_t)(row0 + r) * DIM + k0 + q * 4);
                floatx4 b = *(const floatx4*)(table + (size_t)(n0 + r) * DIM + k0 + q * 4);
                f16x4 ah, al, bh, bl;
#pragma unroll
                for (int j = 0; j < 4; j++) {
                    float pa = (e[j] + n[j]) * SCALE;
                    _Float16 h = (_Float16)pa;
                    ah[j] = h;
                    al[j] = (_Float16)(pa - (float)h);
                    float pb = b[j] * SCALE;
                    _Float16 hb = (_Float16)pb;
                    bh[j] = hb;
                    bl[j] = (_Float16)(pb - (float)hb);
                }
                *(f16x4*)(Ah + r * LDKF + q * 4) = ah;
                *(f16x4*)(Al + r * LDKF + q * 4) = al;
                *(f16x4*)(Bh + r * LDKF + q * 4) = bh;
                *(f16x4*)(Bl + r * LDKF + q * 4) = bl;
            }
            __syncthreads();
#pragma unroll
            for (int ks = 0; ks < BKF; ks += 32) {
                f16x8 bhf[4], blf[4], ahf[4], alf[4];
#pragma unroll
                for (int i = 0; i < 4; i++) {
                    bhf[i] = *(const f16x8*)(Bh + (wn + i * 16 + lq) * LDKF + ks + quad * 8);
                    blf[i] = *(const f16x8*)(Bl + (wn + i * 16 + lq) * LDKF + ks + quad * 8);
                    ahf[i] = *(const f16x8*)(Ah + (wm + i * 16 + lq) * LDKF + ks + quad * 8);
                    alf[i] = *(const f16x8*)(Al + (wm + i * 16 + lq) * LDKF + ks + quad * 8);
                }
#pragma unroll
                for (int mi = 0; mi < 4; mi++)
#pragma unroll
                    for (int ni = 0; ni < 4; ni++) {
                        acc[mi][ni] = __builtin_amdgcn_mfma_f32_16x16x32_f16(
                            ahf[mi], bhf[ni], acc[mi][ni], 0, 0, 0);
                        acc[mi][ni] = __builtin_amdgcn_mfma_f32_16x16x32_f16(
                            ahf[mi], blf[ni], acc[mi][ni], 0, 0, 0);
                        acc[mi][ni] = __builtin_amdgcn_mfma_f32_16x16x32_f16(
                            alf[mi], bhf[ni], acc[mi][ni], 0, 0, 0);
                    }
            }
        }
#pragma unroll
        for (int mi = 0; mi < 4; mi++)
#pragma unroll
            for (int ni = 0; ni < 4; ni++)
#pragma unroll
                for (int r = 0; r < 4; r++) {
                    float v = acc[mi][ni][r];
                    int col = n0 + wn + ni * 16 + n_of[r];
                    int s = mi * 4 + r;
                    if (v > rmax[s] || (v == rmax[s] && col < ridx[s])) {
                        rmax[s] = v;
                        ridx[s] = col;
                    }
                }
    }

#pragma unroll
    for (int s = 0; s < 16; ++s) {
        int mi = s >> 2, r = s & 3;
        int rowl = wm + mi * 16 + m_of[r];
        union { float f; uint32_t i; } u;
        u.f = rmax[s];
        uint32_t ord = (u.i & 0x80000000u) ? ~u.i : (u.i | 0x80000000u);
        unsigned long long key =
            ((unsigned long long)ord << 32) | (uint32_t)(~(uint32_t)ridx[s]);
        atomicMax(&redk[rowl], key);
    }
    __syncthreads();
    if (tid < BM) atomicMax(&keys[row0 + tid], redk[tid]);
}

// ---- gather winning table rows (f32) to output ----
__global__ void gather_kernel(const unsigned long long* __restrict__ keys,
                              const float* __restrict__ table,
                              float* __restrict__ out) {
    int row = blockIdx.x;
    unsigned long long key = keys[row];
    uint32_t ix = ~(uint32_t)(key & 0xFFFFFFFFull);
    const floatx4* src = (const floatx4*)(table + (size_t)ix * DIM);
    floatx4* dst = (floatx4*)(out + (size_t)row * DIM);
    dst[threadIdx.x] = src[threadIdx.x]; // 256 * 16B = 4 KB row
}

extern "C" void kernel_launch(void* const* d_in, const int* in_sizes, int n_in,
                              void* d_out, int out_size, void* d_ws, size_t ws_size,
                              hipStream_t stream) {
    (void)in_sizes; (void)n_in; (void)out_size;
    const float* emb = (const float*)d_in[0];
    const float* table = (const float*)d_in[1];
    const float* noi = (const float*)d_in[2];
    float* out = (float*)d_out;

    uint8_t* ws = (uint8_t*)d_ws;
    unsigned long long* keys = (unsigned long long*)ws;
    const size_t keysB = (size_t)ROWS * 8;
    const size_t aB = (size_t)ROWS * DIM * 2;   // 8.39 MB per A plane
    const size_t bB = (size_t)VOCAB * DIM * 2;  // 65.5 MB per B plane
    const size_t need = keysB + 2 * aB + 2 * bB; // ~141 MB

    init_keys<<<ROWS / 256, 256, 0, stream>>>(keys);

    if (ws_size >= need) {
        _Float16* Ah = (_Float16*)(ws + keysB);
        _Float16* Al = (_Float16*)(ws + keysB + aB);
        _Float16* Bh = (_Float16*)(ws + keysB + 2 * aB);
        _Float16* Bl = (_Float16*)(ws + keysB + 2 * aB + bB);
        split_sum<<<ROWS * DIM / 8 / 256, 256, 0, stream>>>(emb, noi, Ah, Al);
        split_one<<<VOCAB * DIM / 8 / 256, 256, 0, stream>>>(table, Bh, Bl);
        gemm_argmax_pre<<<(ROWS / BM) * NCHUNKS, 256, 0, stream>>>(Ah, Al, Bh, Bl, keys);
    } else {
        gemm_argmax_fused<<<(ROWS / BM) * NCHUNKSF, 256, 0, stream>>>(emb, noi, table, keys);
    }
    gather_kernel<<<ROWS, 256, 0, stream>>>(keys, table, out);
}